// Round 5
// baseline (182.523 us; speedup 1.0000x reference)
//
#include <hip/hip_runtime.h>

typedef __bf16 bf16x8 __attribute__((ext_vector_type(8)));
typedef float floatx4 __attribute__((ext_vector_type(4)));

#define EPSF 1e-6f

__device__ inline unsigned short f2bf(float f) {  // RNE
  union { float f; unsigned u; } x; x.f = f;
  unsigned r = x.u + 0x7FFFu + ((x.u >> 16) & 1u);
  return (unsigned short)(r >> 16);
}
__device__ inline float bf2f(unsigned short u) {
  union { unsigned u; float f; } x; x.u = ((unsigned)u) << 16;
  return x.f;
}
// pack two f32 -> bf16x2 dword, round-half-up
__device__ inline unsigned pk2bf(float lo, float hi) {
  union { float f; unsigned u; } a, b; a.f = lo; b.f = hi;
  unsigned ua = a.u + 0x8000u, ub = b.u + 0x8000u;
  return (ub & 0xFFFF0000u) | (ua >> 16);
}
// single-instruction v_exp_f32 (input in log2 domain — scale folded into Q weights)
__device__ inline float fexp2(float x) { return __builtin_amdgcn_exp2f(x); }

__device__ inline floatx4 mfma16(bf16x8 a, bf16x8 b, floatx4 c) {
  return __builtin_amdgcn_mfma_f32_16x16x32_bf16(a, b, c, 0, 0, 0);
}

__device__ inline void gll16(const unsigned short* g, unsigned short* l) {
  __builtin_amdgcn_global_load_lds((__attribute__((address_space(1))) void*)g,
                                   (__attribute__((address_space(3))) void*)l, 16, 0, 0);
}

// ctx permutation sigma^-1 (PV k-dim): stored pos p in a 32-chunk holds original ctx c
__device__ __host__ inline int sigma_inv(int p) {
  const int qq = p >> 3, jj = p & 7;
  return (jj < 4) ? (qq * 4 + jj) : (16 + qq * 4 + jj - 4);
}

// ---------- merged prep: x cast | qkv_w cast (Q-scaled) | proj_w cast with k-dim gather-perm | policy pack ----------
// feature perm pi(c) = 4*(c%16) + c/16 within each 64-block (qkv GEMM packed epilogue)
__global__ __launch_bounds__(256) void prep_kernel(const float* __restrict__ x,
                                                   const float* __restrict__ qkv_w,
                                                   const float* __restrict__ proj_w,
                                                   const float* __restrict__ policy,
                                                   unsigned short* __restrict__ xb,
                                                   unsigned short* __restrict__ wqkv,
                                                   unsigned short* __restrict__ wproj,
                                                   unsigned short* __restrict__ pbf) {
  const int bid = blockIdx.x, tid = threadIdx.x;
  if (bid < 3072) {  // x cast: 6291456 elems
    const int i = bid * 2048 + tid * 8;
    float4 v0 = *(const float4*)(x + i);
    float4 v1 = *(const float4*)(x + i + 4);
    __align__(16) unsigned short o[8] = {f2bf(v0.x), f2bf(v0.y), f2bf(v0.z), f2bf(v0.w),
                                         f2bf(v1.x), f2bf(v1.y), f2bf(v1.z), f2bf(v1.w)};
    *(float4*)(xb + i) = *(float4*)o;
  } else if (bid < 3936) {  // qkv_w cast: 1769472 elems, first 589824 (Q rows) * 0.125*log2(e)
    const int i = (bid - 3072) * 2048 + tid * 8;
    const float s = (i < 589824) ? 0.18033688011112042f : 1.0f;
    float4 v0 = *(const float4*)(qkv_w + i);
    float4 v1 = *(const float4*)(qkv_w + i + 4);
    __align__(16) unsigned short o[8] = {
        f2bf(v0.x * s), f2bf(v0.y * s), f2bf(v0.z * s), f2bf(v0.w * s),
        f2bf(v1.x * s), f2bf(v1.y * s), f2bf(v1.z * s), f2bf(v1.w * s)};
    *(float4*)(wqkv + i) = *(float4*)o;
  } else if (bid < 4224) {  // proj_w cast with in-dim pi perm: 589824 elems
    const int i0 = (bid - 3936) * 2048 + tid * 8;  // dest index (row-contig)
    const int base = (i0 / 768) * 768 + ((i0 % 768) & ~63);
    __align__(16) unsigned short o[8];
#pragma unroll
    for (int t = 0; t < 8; t++) {
      const int cp = (i0 + t) & 63;                 // stored position within 64-block
      const int c = 16 * (cp & 3) + (cp >> 2);      // original column
      o[t] = f2bf(proj_w[base + c]);
    }
    *(float4*)(wproj + i0) = *(float4*)o;
  } else {  // policy pack: 8192 elems, ctx-perm sigma per 32-chunk
    const int idx = (bid - 4224) * 256 + tid;
    const int b = idx >> 10, g = idx & 1023;
    const int c = ((g >> 5) << 5) + sigma_inv(g & 31);
    pbf[idx] = f2bf(policy[b * 1024 + c]);
  }
}

// ---------- bf16 GEMM: BK=64, XOR-8 swizzle, XCD y-band grid swizzle for L2 locality ----------
// 1D grid; y = (bid&7)*8 + ((bid>>3)&7), x = bid>>6 — XCD k touches one 1024-row A band.
// EP=0 (BN=128): bf16 out with 64-block col-perm pi (packed dwordx2 stores).
// EP=1 (BN=64): f32 out + bias, natural layout.  W = min waves/EU.
template <int EP, int BN, int W>
__global__ __launch_bounds__(256, W) void gemm_bt(const unsigned short* __restrict__ A,
                                                  const unsigned short* __restrict__ Bt,
                                                  void* __restrict__ Cout,
                                                  const float* __restrict__ bias,
                                                  int M, int N, int K) {
  constexpr int J = BN / 32;
  __shared__ __align__(16) unsigned short sA[128 * 64];
  __shared__ __align__(16) unsigned short sB[BN * 64];
  const int bid = blockIdx.x;
  const int yb = (bid & 7) * 8 + ((bid >> 3) & 7);
  const int xb_ = bid >> 6;
  const int m0 = yb * 128, n0 = xb_ * BN;
  const int tid = threadIdx.x;
  const int lane = tid & 63, wave = tid >> 6;
  const int qd = lane >> 4, l15 = lane & 15;
  const int wr = (wave >> 1) * 64, wc = (wave & 1) * (BN / 2);
  const int srow = tid >> 3;
  const int scb = (tid & 7) ^ (srow & 7);
  const unsigned short* Ag = A + (long)(m0 + srow) * K + scb * 8;
  const unsigned short* Bg = Bt + (long)(n0 + srow) * K + scb * 8;
  const int x7 = l15 & 7;
  floatx4 acc[4][J] = {};
  for (int k0 = 0; k0 < K; k0 += 64) {
    __syncthreads();
#pragma unroll
    for (int p = 0; p < 4; p++) gll16(Ag + (long)(p * 32) * K + k0, sA + p * 2048 + wave * 512);
#pragma unroll
    for (int p = 0; p < J; p++) gll16(Bg + (long)(p * 32) * K + k0, sB + p * 2048 + wave * 512);
    __syncthreads();
#pragma unroll
    for (int s = 0; s < 2; s++) {
      const int cw = ((s * 4 + qd) ^ x7) * 8;
      bf16x8 af[4], bf[J];
#pragma unroll
      for (int i = 0; i < 4; i++) af[i] = *(const bf16x8*)&sA[(wr + i * 16 + l15) * 64 + cw];
#pragma unroll
      for (int j = 0; j < J; j++) bf[j] = *(const bf16x8*)&sB[(wc + j * 16 + l15) * 64 + cw];
#pragma unroll
      for (int i = 0; i < 4; i++)
#pragma unroll
        for (int j = 0; j < J; j++) acc[i][j] = mfma16(af[i], bf[j], acc[i][j]);
    }
  }
  if constexpr (EP == 0) {
    // feature f = wc + 16j + l15 stored at col' = wc + 4*l15 + j  (pi within 64-block)
#pragma unroll
    for (int i = 0; i < 4; i++)
#pragma unroll
      for (int r = 0; r < 4; r++) {
        const int row = m0 + wr + i * 16 + qd * 4 + r;
        __align__(8) unsigned short pk[4];
#pragma unroll
        for (int j = 0; j < 4; j++) pk[j] = f2bf(acc[i][j][r]);
        *(uint2*)((unsigned short*)Cout + (long)row * N + n0 + wc + 4 * l15) = *(uint2*)pk;
      }
  } else {
#pragma unroll
    for (int i = 0; i < 4; i++)
#pragma unroll
      for (int j = 0; j < J; j++) {
        const int col = n0 + wc + j * 16 + l15;
#pragma unroll
        for (int r = 0; r < 4; r++) {
          const int row = m0 + wr + i * 16 + qd * 4 + r;
          ((float*)Cout)[(long)row * N + col] = acc[i][j][r] + bias[col];
        }
      }
  }
}

// ---------- V transpose + policy fold + ctx sigma-perm ----------
__global__ __launch_bounds__(256) void transpose_v(const unsigned short* __restrict__ qkv,
                                                   const float* __restrict__ policy,
                                                   unsigned short* __restrict__ vTp) {
  __shared__ unsigned short tile[64][72];
  __shared__ float sPol[64];
  const int bh = blockIdx.y;
  const int b = bh / 12, h = bh % 12;
  const int n0 = blockIdx.x * 64;
  const int t = threadIdx.x;
  if (t < 64) sPol[t] = policy[b * 1024 + n0 + t];
  {
    const int nr = t >> 2, dc = (t & 3) * 16;
    const unsigned short* src = qkv + (long)(b * 1024 + n0 + nr) * 2304 + 2 * 768 + h * 64 + dc;
    float4 v0 = *(const float4*)src;
    float4 v1 = *(const float4*)(src + 8);
    *(float4*)&tile[nr][dc] = v0;
    *(float4*)&tile[nr][dc + 8] = v1;
  }
  __syncthreads();
  {
    const int d = t >> 2, nc = (t & 3) * 16;
    __align__(16) unsigned short o[16];
#pragma unroll
    for (int jj = 0; jj < 16; jj++) {
      const int cc = nc + jj;
      const int cl = (cc & 32) + sigma_inv(cc & 31);
      o[jj] = f2bf(bf2f(tile[cl][d]) * sPol[cl]);
    }
    unsigned short* dst = vTp + (long)(bh * 64 + d) * 1024 + n0 + nc;
    *(float4*)dst = *(float4*)&o[0];
    *(float4*)(dst + 8) = *(float4*)&o[8];
  }
}

// ---------- attention v17: 64 q per wave, 2-wave blocks — halve LDS-read traffic ----------
// History: v8 42us | v12 100us FAIL (reg-direct uncoalesced) | v13/v14 NULL (sync axis dead) |
//   v16 41.0us (reg-K prefetch + raw barrier + counted vmcnt; small win).
// Diagnosis (v16 counters): LDS reads = largest pipe term (12 waves/CU x 9 ds_read_b128 x 12cy
//   ~= 42% of wall); K/V frags are IDENTICAL across a block's waves (depend only on l15,qd,chunk)
//   => 4-wave blocks read each chunk 4x. Classic B-operand redundancy; fix = bigger Q tile/wave.
// v17: 128-thr blocks, 2 waves x 64q (4 x 16q subtiles). Chunk-visits per block: 4 -> 2
//   (LDS read cycles halve). MFMA/VALU totals unchanged. 3-deep staging, 4 DMAs/chunk/wave,
//   vmcnt(4) counted wait + raw barrier. PV interleaved per-subtile with exp/pack (VGPR + pipe mix).
__global__ __launch_bounds__(128, 2) void attn_kernel(const unsigned short* __restrict__ qkv,
                                                      const unsigned short* __restrict__ vTp,
                                                      const unsigned short* __restrict__ pbf,
                                                      const float* __restrict__ policy,
                                                      unsigned short* __restrict__ aout) {
  __shared__ __align__(16) unsigned short sK[4][2048];  // 32 ctx x 64 d, slot cb = c ^ (row&7)
  __shared__ __align__(16) unsigned short sV[4][2048];  // 64 d x 32 ctx, slot cb = c ^ ((d^(d>>2))&3)
  __shared__ __align__(16) unsigned short sPv[1024];
  __shared__ float sD[2][64];
  const int bid = blockIdx.x;
  const int bh = bid % 96, qt = bid / 96;  // bh-fast for XCD L2 locality
  const int b = bh / 12, h = bh % 12;
  const int tid = threadIdx.x;
  const int wave = tid >> 6, lane = tid & 63;
  const int qd = lane >> 4, l15 = lane & 15;
  const int q0 = qt * 128 + wave * 64;  // 64 q per wave
  const unsigned short* qb = qkv + (long)(b * 1024 + q0 + l15) * 2304 + h * 64 + qd * 8;
  bf16x8 qf[4][2];  // Q pre-scaled by 0.125*log2e; [subtile m][d-half]
#pragma unroll
  for (int m = 0; m < 4; m++) {
    qf[m][0] = *(const bf16x8*)(qb + (long)(m * 16) * 2304);
    qf[m][1] = *(const bf16x8*)(qb + (long)(m * 16) * 2304 + 32);
  }
  *(float4*)(sPv + tid * 8) = *(const float4*)(pbf + b * 1024 + tid * 8);
  // K staging: 2 parts per wave; part p covers rows p*16 + wave*8 + (lane>>3)
  const int krow = wave * 8 + (lane >> 3);
  const int kcb = (lane & 7) ^ (lane >> 3);  // (row&7) == lane>>3 for all parts
  const unsigned short* kgl = qkv + (long)(b * 1024 + krow) * 2304 + 768 + h * 64 + kcb * 8;
  // V staging: 2 parts per wave; part p covers d-rows p*32 + (tid>>2)
  const int vrow = tid >> 2;
  const int vcb = (tid & 3) ^ ((vrow ^ (vrow >> 2)) & 3);  // invariant under +32 rows
  const unsigned short* vgl = vTp + (long)(bh * 64 + vrow) * 1024 + vcb * 8;
  const int x7 = l15 & 7;
  const int vsw = (qd ^ ((l15 ^ (l15 >> 2)) & 3)) * 8;
  floatx4 O[4][4] = {};  // [subtile m][d-block j]
  floatx4 Dl[4] = {};
  const floatx4 z = {0.f, 0.f, 0.f, 0.f};
  // prologue: stage chunks 0..2 (3-deep, 4 DMAs each); vmcnt(4) => chunks 0,1 landed
#pragma unroll
  for (int c = 0; c < 3; ++c) {
    gll16(kgl + (long)(32 * c) * 2304, &sK[c][wave * 512]);
    gll16(kgl + (long)(32 * c + 16) * 2304, &sK[c][1024 + wave * 512]);
    gll16(vgl + 32 * c, &sV[c][wave * 512]);
    gll16(vgl + (long)32 * 1024 + 32 * c, &sV[c][1024 + wave * 512]);
  }
  asm volatile("s_waitcnt vmcnt(4) lgkmcnt(0)" ::: "memory");
  __builtin_amdgcn_s_barrier();
  asm volatile("" ::: "memory");
  // preload K[0] fragments into registers
  bf16x8 kf00 = *(const bf16x8*)&sK[0][(0 + l15) * 64 + ((0 + qd) ^ x7) * 8];
  bf16x8 kf01 = *(const bf16x8*)&sK[0][(0 + l15) * 64 + ((4 + qd) ^ x7) * 8];
  bf16x8 kf10 = *(const bf16x8*)&sK[0][(16 + l15) * 64 + ((0 + qd) ^ x7) * 8];
  bf16x8 kf11 = *(const bf16x8*)&sK[0][(16 + l15) * 64 + ((4 + qd) ^ x7) * 8];
  for (int it = 0; it < 32; ++it) {
    const int buf = it & 3;
    if (it < 29) {  // stage chunk it+3 (4 DMAs) — in flight across this iteration's barrier
      const long co = (long)(32 * (it + 3));
      const int nb3 = (it + 3) & 3;
      gll16(kgl + co * 2304, &sK[nb3][wave * 512]);
      gll16(kgl + (co + 16) * 2304, &sK[nb3][1024 + wave * 512]);
      gll16(vgl + co, &sV[nb3][wave * 512]);
      gll16(vgl + (long)32 * 1024 + co, &sV[nb3][1024 + wave * 512]);
    }
    const int c0 = it * 32;
    bf16x8 pv = *(const bf16x8*)&sPv[c0 + qd * 8];
    // S^T = K·Q^T from REGISTER K fragments (shared across all 4 q-subtiles)
    floatx4 tA[4], tB[4];
    __builtin_amdgcn_s_setprio(1);
#pragma unroll
    for (int m = 0; m < 4; m++) {
      tA[m] = mfma16(kf01, qf[m][1], mfma16(kf00, qf[m][0], z));
      tB[m] = mfma16(kf11, qf[m][1], mfma16(kf10, qf[m][0], z));
    }
    __builtin_amdgcn_s_setprio(0);
    // prefetch next chunk's K frags (landed by prev barrier) — retires under exp/pack
    const int nb = (it + 1) & 3;  // at it=31 reads stale buf 0: values dead, no hazard
    bf16x8 nk00 = *(const bf16x8*)&sK[nb][(0 + l15) * 64 + ((0 + qd) ^ x7) * 8];
    bf16x8 nk01 = *(const bf16x8*)&sK[nb][(0 + l15) * 64 + ((4 + qd) ^ x7) * 8];
    bf16x8 nk10 = *(const bf16x8*)&sK[nb][(16 + l15) * 64 + ((0 + qd) ^ x7) * 8];
    bf16x8 nk11 = *(const bf16x8*)&sK[nb][(16 + l15) * 64 + ((4 + qd) ^ x7) * 8];
    bf16x8 vf0 = *(const bf16x8*)&sV[buf][(0 * 16 + l15) * 32 + vsw];
    bf16x8 vf1 = *(const bf16x8*)&sV[buf][(1 * 16 + l15) * 32 + vsw];
    bf16x8 vf2 = *(const bf16x8*)&sV[buf][(2 * 16 + l15) * 32 + vsw];
    bf16x8 vf3 = *(const bf16x8*)&sV[buf][(3 * 16 + l15) * 32 + vsw];
    // per-subtile: exp/pack (VALU) interleaved with PV (MFMA) of previous subtile
#pragma unroll
    for (int m = 0; m < 4; m++) {
      uint4 pu;
      pu.x = pk2bf(fexp2(tA[m][0]), fexp2(tA[m][1]));
      pu.y = pk2bf(fexp2(tA[m][2]), fexp2(tA[m][3]));
      pu.z = pk2bf(fexp2(tB[m][0]), fexp2(tB[m][1]));
      pu.w = pk2bf(fexp2(tB[m][2]), fexp2(tB[m][3]));
      bf16x8 pf = *(bf16x8*)&pu;
      Dl[m] = mfma16(pf, pv, Dl[m]);
      O[m][0] = mfma16(pf, vf0, O[m][0]);
      O[m][1] = mfma16(pf, vf1, O[m][1]);
      O[m][2] = mfma16(pf, vf2, O[m][2]);
      O[m][3] = mfma16(pf, vf3, O[m][3]);
    }
    kf00 = nk00; kf01 = nk01; kf10 = nk10; kf11 = nk11;
    // counted wait before RAW barrier: retire chunk it+2; newest chunk stays in flight
    if (it < 29) asm volatile("s_waitcnt vmcnt(4)" ::: "memory");
    else         asm volatile("s_waitcnt vmcnt(0)" ::: "memory");
    __builtin_amdgcn_s_barrier();
    asm volatile("" ::: "memory");
  }
  // ---- diagonal correction: O[q] += e_qq(1-p_q) V[q]; l_q += e_qq(1-p_q) ----
  {
#pragma unroll
    for (int m = 0; m < 4; m++) {
      const unsigned short* kd =
          qkv + (long)(b * 1024 + q0 + m * 16 + l15) * 2304 + 768 + h * 64 + qd * 8;
      bf16x8 kd0 = *(const bf16x8*)kd;
      bf16x8 kd1 = *(const bf16x8*)(kd + 32);
      float pt = 0.f;
#pragma unroll
      for (int jj = 0; jj < 8; jj++)
        pt += (float)qf[m][0][jj] * (float)kd0[jj] + (float)qf[m][1][jj] * (float)kd1[jj];
      pt += __shfl_xor(pt, 16);
      pt += __shfl_xor(pt, 32);
      const float pm = policy[b * 1024 + q0 + m * 16 + l15];
      if (qd == 0) sD[wave][m * 16 + l15] = fexp2(pt) * (1.0f - pm);
    }
    __builtin_amdgcn_s_waitcnt(0);
    const unsigned short* vdiag = qkv + (long)(b * 1024 + q0) * 2304 + 1536 + h * 64 + l15;
#pragma unroll
    for (int m = 0; m < 4; m++)
#pragma unroll
      for (int r = 0; r < 4; r++) {
        const int row = m * 16 + qd * 4 + r;
        const float cv = sD[wave][row];
#pragma unroll
        for (int j = 0; j < 4; j++) O[m][j][r] += cv * bf2f(vdiag[(long)row * 2304 + j * 16]);
        Dl[m][r] += cv;
      }
  }
#pragma unroll
  for (int m = 0; m < 4; m++) {
    const long ob = (long)(b * 1024 + q0 + m * 16 + qd * 4) * 768 + h * 64 + l15;
#pragma unroll
    for (int r = 0; r < 4; r++) {
      const float li = 1.0f / (Dl[m][r] + EPSF);
#pragma unroll
      for (int j = 0; j < 4; j++) aout[ob + (long)r * 768 + j * 16] = f2bf(O[m][j][r] * li);
    }
  }
}

extern "C" void kernel_launch(void* const* d_in, const int* in_sizes, int n_in,
                              void* d_out, int out_size, void* d_ws, size_t ws_size,
                              hipStream_t stream) {
  const float* x      = (const float*)d_in[0];   // [8,1024,768]
  const float* policy = (const float*)d_in[1];   // [8,1024,1]
  const float* qkv_w  = (const float*)d_in[2];   // [2304,768]
  const float* proj_w = (const float*)d_in[3];   // [768,768]
  const float* proj_b = (const float*)d_in[4];   // [768]
  float* out = (float*)d_out;                    // [8,1024,768] fp32

  char* ws = (char*)d_ws;
  unsigned short* xb    = (unsigned short*)(ws + 0);         // 12,582,912 B
  unsigned short* wqkv  = (unsigned short*)(ws + 12582912);  //  3,538,944 B
  unsigned short* wproj = (unsigned short*)(ws + 16121856);  //  1,179,648 B
  unsigned short* qkvb  = (unsigned short*)(ws + 17301504);  // 37,748,736 B
  unsigned short* vTp   = (unsigned short*)(ws + 55050240);  // 12,582,912 B
  unsigned short* aoutb = (unsigned short*)(ws + 67633152);  // 12,582,912 B
  unsigned short* pbf   = (unsigned short*)(ws + 80216064);  //     16,384 B

  prep_kernel<<<4256, 256, 0, stream>>>(x, qkv_w, proj_w, policy, xb, wqkv, wproj, pbf);
  gemm_bt<0, 128, 4><<<dim3(18 * 64), 256, 0, stream>>>(xb, wqkv, qkvb, nullptr, 8192, 2304, 768);
  transpose_v<<<dim3(16, 96), 256, 0, stream>>>(qkvb, policy, vTp);
  attn_kernel<<<dim3(768), 128, 0, stream>>>(qkvb, vTp, pbf, policy, aoutb);
  gemm_bt<1, 64, 3><<<dim3(12 * 64), 256, 0, stream>>>(aoutb, wproj, out, proj_b, 8192, 768, 768);
}

// Round 6
// 177.657 us; speedup vs baseline: 1.0274x; 1.0274x over previous
//
#include <hip/hip_runtime.h>

typedef __bf16 bf16x8 __attribute__((ext_vector_type(8)));
typedef float floatx4 __attribute__((ext_vector_type(4)));

#define EPSF 1e-6f

__device__ inline unsigned short f2bf(float f) {  // RNE
  union { float f; unsigned u; } x; x.f = f;
  unsigned r = x.u + 0x7FFFu + ((x.u >> 16) & 1u);
  return (unsigned short)(r >> 16);
}
__device__ inline float bf2f(unsigned short u) {
  union { unsigned u; float f; } x; x.u = ((unsigned)u) << 16;
  return x.f;
}
// pack two f32 -> bf16x2 dword, round-half-up (prep/gemm epilogue path)
__device__ inline unsigned pk2bf(float lo, float hi) {
  union { float f; unsigned u; } a, b; a.f = lo; b.f = hi;
  unsigned ua = a.u + 0x8000u, ub = b.u + 0x8000u;
  return (ub & 0xFFFF0000u) | (ua >> 16);
}
// HW packed f32x2 -> bf16x2 (RNE) — single VALU instr, no builtin on gfx950 (T12/m240)
__device__ inline unsigned cvtpk(float lo, float hi) {
  unsigned r;
  asm("v_cvt_pk_bf16_f32 %0, %1, %2" : "=v"(r) : "v"(lo), "v"(hi));
  return r;
}
// single-instruction v_exp_f32 (input in log2 domain — scale folded into Q weights)
__device__ inline float fexp2(float x) { return __builtin_amdgcn_exp2f(x); }

__device__ inline floatx4 mfma16(bf16x8 a, bf16x8 b, floatx4 c) {
  return __builtin_amdgcn_mfma_f32_16x16x32_bf16(a, b, c, 0, 0, 0);
}

__device__ inline void gll16(const unsigned short* g, unsigned short* l) {
  __builtin_amdgcn_global_load_lds((__attribute__((address_space(1))) void*)g,
                                   (__attribute__((address_space(3))) void*)l, 16, 0, 0);
}

// ctx permutation sigma^-1 (PV k-dim): stored pos p in a 32-chunk holds original ctx c
__device__ __host__ inline int sigma_inv(int p) {
  const int qq = p >> 3, jj = p & 7;
  return (jj < 4) ? (qq * 4 + jj) : (16 + qq * 4 + jj - 4);
}

// ---------- merged prep: x cast | qkv_w cast (Q-scaled) | proj_w cast with k-dim gather-perm | policy pack ----------
// feature perm pi(c) = 4*(c%16) + c/16 within each 64-block (qkv GEMM packed epilogue)
__global__ __launch_bounds__(256) void prep_kernel(const float* __restrict__ x,
                                                   const float* __restrict__ qkv_w,
                                                   const float* __restrict__ proj_w,
                                                   const float* __restrict__ policy,
                                                   unsigned short* __restrict__ xb,
                                                   unsigned short* __restrict__ wqkv,
                                                   unsigned short* __restrict__ wproj,
                                                   unsigned short* __restrict__ pbf) {
  const int bid = blockIdx.x, tid = threadIdx.x;
  if (bid < 3072) {  // x cast: 6291456 elems
    const int i = bid * 2048 + tid * 8;
    float4 v0 = *(const float4*)(x + i);
    float4 v1 = *(const float4*)(x + i + 4);
    __align__(16) unsigned short o[8] = {f2bf(v0.x), f2bf(v0.y), f2bf(v0.z), f2bf(v0.w),
                                         f2bf(v1.x), f2bf(v1.y), f2bf(v1.z), f2bf(v1.w)};
    *(float4*)(xb + i) = *(float4*)o;
  } else if (bid < 3936) {  // qkv_w cast: 1769472 elems, first 589824 (Q rows) * 0.125*log2(e)
    const int i = (bid - 3072) * 2048 + tid * 8;
    const float s = (i < 589824) ? 0.18033688011112042f : 1.0f;
    float4 v0 = *(const float4*)(qkv_w + i);
    float4 v1 = *(const float4*)(qkv_w + i + 4);
    __align__(16) unsigned short o[8] = {
        f2bf(v0.x * s), f2bf(v0.y * s), f2bf(v0.z * s), f2bf(v0.w * s),
        f2bf(v1.x * s), f2bf(v1.y * s), f2bf(v1.z * s), f2bf(v1.w * s)};
    *(float4*)(wqkv + i) = *(float4*)o;
  } else if (bid < 4224) {  // proj_w cast with in-dim pi perm: 589824 elems
    const int i0 = (bid - 3936) * 2048 + tid * 8;  // dest index (row-contig)
    const int base = (i0 / 768) * 768 + ((i0 % 768) & ~63);
    __align__(16) unsigned short o[8];
#pragma unroll
    for (int t = 0; t < 8; t++) {
      const int cp = (i0 + t) & 63;                 // stored position within 64-block
      const int c = 16 * (cp & 3) + (cp >> 2);      // original column
      o[t] = f2bf(proj_w[base + c]);
    }
    *(float4*)(wproj + i0) = *(float4*)o;
  } else {  // policy pack: 8192 elems, ctx-perm sigma per 32-chunk
    const int idx = (bid - 4224) * 256 + tid;
    const int b = idx >> 10, g = idx & 1023;
    const int c = ((g >> 5) << 5) + sigma_inv(g & 31);
    pbf[idx] = f2bf(policy[b * 1024 + c]);
  }
}

// ---------- bf16 GEMM: BK=64, XOR-8 swizzle, XCD y-band grid swizzle for L2 locality ----------
// 1D grid; y = (bid&7)*8 + ((bid>>3)&7), x = bid>>6 — XCD k touches one 1024-row A band.
// EP=0 (BN=128): bf16 out with 64-block col-perm pi (packed dwordx2 stores).
// EP=1 (BN=64): f32 out + bias, natural layout.  W = min waves/EU.
template <int EP, int BN, int W>
__global__ __launch_bounds__(256, W) void gemm_bt(const unsigned short* __restrict__ A,
                                                  const unsigned short* __restrict__ Bt,
                                                  void* __restrict__ Cout,
                                                  const float* __restrict__ bias,
                                                  int M, int N, int K) {
  constexpr int J = BN / 32;
  __shared__ __align__(16) unsigned short sA[128 * 64];
  __shared__ __align__(16) unsigned short sB[BN * 64];
  const int bid = blockIdx.x;
  const int yb = (bid & 7) * 8 + ((bid >> 3) & 7);
  const int xb_ = bid >> 6;
  const int m0 = yb * 128, n0 = xb_ * BN;
  const int tid = threadIdx.x;
  const int lane = tid & 63, wave = tid >> 6;
  const int qd = lane >> 4, l15 = lane & 15;
  const int wr = (wave >> 1) * 64, wc = (wave & 1) * (BN / 2);
  const int srow = tid >> 3;
  const int scb = (tid & 7) ^ (srow & 7);
  const unsigned short* Ag = A + (long)(m0 + srow) * K + scb * 8;
  const unsigned short* Bg = Bt + (long)(n0 + srow) * K + scb * 8;
  const int x7 = l15 & 7;
  floatx4 acc[4][J] = {};
  for (int k0 = 0; k0 < K; k0 += 64) {
    __syncthreads();
#pragma unroll
    for (int p = 0; p < 4; p++) gll16(Ag + (long)(p * 32) * K + k0, sA + p * 2048 + wave * 512);
#pragma unroll
    for (int p = 0; p < J; p++) gll16(Bg + (long)(p * 32) * K + k0, sB + p * 2048 + wave * 512);
    __syncthreads();
#pragma unroll
    for (int s = 0; s < 2; s++) {
      const int cw = ((s * 4 + qd) ^ x7) * 8;
      bf16x8 af[4], bf[J];
#pragma unroll
      for (int i = 0; i < 4; i++) af[i] = *(const bf16x8*)&sA[(wr + i * 16 + l15) * 64 + cw];
#pragma unroll
      for (int j = 0; j < J; j++) bf[j] = *(const bf16x8*)&sB[(wc + j * 16 + l15) * 64 + cw];
#pragma unroll
      for (int i = 0; i < 4; i++)
#pragma unroll
        for (int j = 0; j < J; j++) acc[i][j] = mfma16(af[i], bf[j], acc[i][j]);
    }
  }
  if constexpr (EP == 0) {
    // feature f = wc + 16j + l15 stored at col' = wc + 4*l15 + j  (pi within 64-block)
#pragma unroll
    for (int i = 0; i < 4; i++)
#pragma unroll
      for (int r = 0; r < 4; r++) {
        const int row = m0 + wr + i * 16 + qd * 4 + r;
        __align__(8) unsigned short pk[4];
#pragma unroll
        for (int j = 0; j < 4; j++) pk[j] = f2bf(acc[i][j][r]);
        *(uint2*)((unsigned short*)Cout + (long)row * N + n0 + wc + 4 * l15) = *(uint2*)pk;
      }
  } else {
#pragma unroll
    for (int i = 0; i < 4; i++)
#pragma unroll
      for (int j = 0; j < J; j++) {
        const int col = n0 + wc + j * 16 + l15;
#pragma unroll
        for (int r = 0; r < 4; r++) {
          const int row = m0 + wr + i * 16 + qd * 4 + r;
          ((float*)Cout)[(long)row * N + col] = acc[i][j][r] + bias[col];
        }
      }
  }
}

// ---------- V transpose + policy fold + ctx sigma-perm ----------
__global__ __launch_bounds__(256) void transpose_v(const unsigned short* __restrict__ qkv,
                                                   const float* __restrict__ policy,
                                                   unsigned short* __restrict__ vTp) {
  __shared__ unsigned short tile[64][72];
  __shared__ float sPol[64];
  const int bh = blockIdx.y;
  const int b = bh / 12, h = bh % 12;
  const int n0 = blockIdx.x * 64;
  const int t = threadIdx.x;
  if (t < 64) sPol[t] = policy[b * 1024 + n0 + t];
  {
    const int nr = t >> 2, dc = (t & 3) * 16;
    const unsigned short* src = qkv + (long)(b * 1024 + n0 + nr) * 2304 + 2 * 768 + h * 64 + dc;
    float4 v0 = *(const float4*)src;
    float4 v1 = *(const float4*)(src + 8);
    *(float4*)&tile[nr][dc] = v0;
    *(float4*)&tile[nr][dc + 8] = v1;
  }
  __syncthreads();
  {
    const int d = t >> 2, nc = (t & 3) * 16;
    __align__(16) unsigned short o[16];
#pragma unroll
    for (int jj = 0; jj < 16; jj++) {
      const int cc = nc + jj;
      const int cl = (cc & 32) + sigma_inv(cc & 31);
      o[jj] = f2bf(bf2f(tile[cl][d]) * sPol[cl]);
    }
    unsigned short* dst = vTp + (long)(bh * 64 + d) * 1024 + n0 + nc;
    *(float4*)dst = *(float4*)&o[0];
    *(float4*)(dst + 8) = *(float4*)&o[8];
  }
}

// ---------- attention v18: v16 + ping-pong unroll (kills 16 v_mov/iter) + v_cvt_pk_bf16_f32 ----------
// History: v8 42us | v12 100us FAIL (reg-direct uncoalesced) | v13/v14 NULL (sync axis dead) |
//   v16 41.0us WIN (reg-K prefetch + raw barrier + counted vmcnt) |
//   v17 51.5us FAIL (64q/wave halves LDS traffic as predicted — conflicts 1.57M->786K — but
//   wave count is work-bound: 6 waves/CU, ~16us latency bubbles. TLP > LDS-traffic. Reverted.)
// v18: structure = v16 (32q/wave, 4 waves, 12 waves/CU). VALU diet only:
//   (a) 2x unroll with named frag sets A/B — removes the kf=nk register copies (~32 cy/wave-iter);
//   (b) v_cvt_pk_bf16_f32 packing (RNE) — 1 instr per bf16 pair vs ~4 int ops (~48 cy/wave-iter).
__global__ __launch_bounds__(256, 3) void attn_kernel(const unsigned short* __restrict__ qkv,
                                                      const unsigned short* __restrict__ vTp,
                                                      const unsigned short* __restrict__ pbf,
                                                      const float* __restrict__ policy,
                                                      unsigned short* __restrict__ aout) {
  __shared__ __align__(16) unsigned short sK[4][2048];  // 32 ctx x 64 d, slot cb = c ^ (row&7)
  __shared__ __align__(16) unsigned short sV[4][2048];  // 64 d x 32 ctx, slot cb = c ^ ((d^(d>>2))&3)
  __shared__ __align__(16) unsigned short sPv[1024];
  __shared__ float sD[4][32];
  const int bid = blockIdx.x;
  const int bh = bid % 96, qt = bid / 96;  // bh-fast for XCD L2 locality
  const int b = bh / 12, h = bh % 12;
  const int tid = threadIdx.x;
  const int wave = tid >> 6, lane = tid & 63;
  const int qd = lane >> 4, l15 = lane & 15;
  const int q0 = qt * 128 + wave * 32;
  const unsigned short* qb = qkv + (long)(b * 1024 + q0 + l15) * 2304 + h * 64 + qd * 8;
  bf16x8 qf00 = *(const bf16x8*)qb;  // Q pre-scaled by 0.125*log2e
  bf16x8 qf01 = *(const bf16x8*)(qb + 32);
  bf16x8 qf10 = *(const bf16x8*)(qb + (long)16 * 2304);
  bf16x8 qf11 = *(const bf16x8*)(qb + (long)16 * 2304 + 32);
  if (tid < 128) *(float4*)(sPv + tid * 8) = *(const float4*)(pbf + b * 1024 + tid * 8);
  const int krow = wave * 8 + (lane >> 3);
  const int kcb = (lane & 7) ^ (lane >> 3);
  const unsigned short* kgl = qkv + (long)(b * 1024 + krow) * 2304 + 768 + h * 64 + kcb * 8;
  const int vrow = tid >> 2;
  const int vcb = (tid & 3) ^ ((vrow ^ (vrow >> 2)) & 3);
  const unsigned short* vgl = vTp + (long)(bh * 64 + vrow) * 1024 + vcb * 8;
  const int x7 = l15 & 7;
  const int vsw = (qd ^ ((l15 ^ (l15 >> 2)) & 3)) * 8;
  floatx4 O0[4] = {}, O1[4] = {};
  floatx4 Dl0 = {}, Dl1 = {};
  const floatx4 z = {0.f, 0.f, 0.f, 0.f};
  // prologue: stage chunks 0..2 (3-deep); vmcnt(2) => chunks 0,1 landed, chunk 2 in flight
#pragma unroll
  for (int c = 0; c < 3; ++c) {
    gll16(kgl + (long)(32 * c) * 2304, &sK[c][wave * 512]);
    gll16(vgl + 32 * c, &sV[c][wave * 512]);
  }
  asm volatile("s_waitcnt vmcnt(2) lgkmcnt(0)" ::: "memory");
  __builtin_amdgcn_s_barrier();
  asm volatile("" ::: "memory");
  // preload K[0] fragments into register set A
  bf16x8 kA00 = *(const bf16x8*)&sK[0][(0 + l15) * 64 + ((0 + qd) ^ x7) * 8];
  bf16x8 kA01 = *(const bf16x8*)&sK[0][(0 + l15) * 64 + ((4 + qd) ^ x7) * 8];
  bf16x8 kA10 = *(const bf16x8*)&sK[0][(16 + l15) * 64 + ((0 + qd) ^ x7) * 8];
  bf16x8 kA11 = *(const bf16x8*)&sK[0][(16 + l15) * 64 + ((4 + qd) ^ x7) * 8];
  bf16x8 kB00, kB01, kB10, kB11;
  // one iteration body: consumes frag set "c", prefetches next chunk's frags into set "n"
  auto body = [&](int it, bf16x8& c00, bf16x8& c01, bf16x8& c10, bf16x8& c11,
                  bf16x8& n00, bf16x8& n01, bf16x8& n10, bf16x8& n11) {
    const int buf = it & 3;
    if (it < 29) {  // stage chunk it+3 into buf (it+3)&3 (reads of that buf done pre-barrier)
      const long co = (long)(32 * (it + 3));
      gll16(kgl + co * 2304, &sK[(it + 3) & 3][wave * 512]);
      gll16(vgl + co, &sV[(it + 3) & 3][wave * 512]);
    }
    const int c0 = it * 32;
    bf16x8 pv = *(const bf16x8*)&sPv[c0 + qd * 8];
    // S^T = K·Q^T from REGISTER K — issues immediately after barrier, no LDS head
    __builtin_amdgcn_s_setprio(1);
    floatx4 tA0 = mfma16(c01, qf01, mfma16(c00, qf00, z));
    floatx4 tB0 = mfma16(c11, qf01, mfma16(c10, qf00, z));
    floatx4 tA1 = mfma16(c01, qf11, mfma16(c00, qf10, z));
    floatx4 tB1 = mfma16(c11, qf11, mfma16(c10, qf10, z));
    __builtin_amdgcn_s_setprio(0);
    // prefetch next chunk's K frags (chunk it+1 landed by prev barrier) — retires under exp/pack
    const int nb = (it + 1) & 3;  // at it=31 reads stale buf 0: values dead, no hazard
    n00 = *(const bf16x8*)&sK[nb][(0 + l15) * 64 + ((0 + qd) ^ x7) * 8];
    n01 = *(const bf16x8*)&sK[nb][(0 + l15) * 64 + ((4 + qd) ^ x7) * 8];
    n10 = *(const bf16x8*)&sK[nb][(16 + l15) * 64 + ((0 + qd) ^ x7) * 8];
    n11 = *(const bf16x8*)&sK[nb][(16 + l15) * 64 + ((4 + qd) ^ x7) * 8];
    uint4 pu0, pu1;
    pu0.x = cvtpk(fexp2(tA0[0]), fexp2(tA0[1]));
    pu0.y = cvtpk(fexp2(tA0[2]), fexp2(tA0[3]));
    pu0.z = cvtpk(fexp2(tB0[0]), fexp2(tB0[1]));
    pu0.w = cvtpk(fexp2(tB0[2]), fexp2(tB0[3]));
    pu1.x = cvtpk(fexp2(tA1[0]), fexp2(tA1[1]));
    pu1.y = cvtpk(fexp2(tA1[2]), fexp2(tA1[3]));
    pu1.z = cvtpk(fexp2(tB1[0]), fexp2(tB1[1]));
    pu1.w = cvtpk(fexp2(tB1[2]), fexp2(tB1[3]));
    bf16x8 pf0 = *(bf16x8*)&pu0;
    bf16x8 pf1 = *(bf16x8*)&pu1;
    bf16x8 vf0 = *(const bf16x8*)&sV[buf][(0 * 16 + l15) * 32 + vsw];
    bf16x8 vf1 = *(const bf16x8*)&sV[buf][(1 * 16 + l15) * 32 + vsw];
    bf16x8 vf2 = *(const bf16x8*)&sV[buf][(2 * 16 + l15) * 32 + vsw];
    bf16x8 vf3 = *(const bf16x8*)&sV[buf][(3 * 16 + l15) * 32 + vsw];
    __builtin_amdgcn_s_setprio(1);
    Dl0 = mfma16(pf0, pv, Dl0);
    Dl1 = mfma16(pf1, pv, Dl1);
    O0[0] = mfma16(pf0, vf0, O0[0]); O1[0] = mfma16(pf1, vf0, O1[0]);
    O0[1] = mfma16(pf0, vf1, O0[1]); O1[1] = mfma16(pf1, vf1, O1[1]);
    O0[2] = mfma16(pf0, vf2, O0[2]); O1[2] = mfma16(pf1, vf2, O1[2]);
    O0[3] = mfma16(pf0, vf3, O0[3]); O1[3] = mfma16(pf1, vf3, O1[3]);
    __builtin_amdgcn_s_setprio(0);
    // counted wait: retire chunk it+2 (needed next iter for reg-prefetch); newest 2 stay in flight
    if (it < 29) asm volatile("s_waitcnt vmcnt(2)" ::: "memory");
    else         asm volatile("s_waitcnt vmcnt(0)" ::: "memory");
    __builtin_amdgcn_s_barrier();
    asm volatile("" ::: "memory");
  };
  // 2x-unrolled ping-pong: even iters consume set A / fill set B; odd consume B / fill A.
#pragma unroll 1
  for (int itp = 0; itp < 16; ++itp) {
    body(2 * itp,     kA00, kA01, kA10, kA11, kB00, kB01, kB10, kB11);
    body(2 * itp + 1, kB00, kB01, kB10, kB11, kA00, kA01, kA10, kA11);
  }
  // ---- diagonal correction: O[q] += e_qq(1-p_q) V[q]; l_q += e_qq(1-p_q) ----
  {
    const unsigned short* kd = qkv + (long)(b * 1024 + q0 + l15) * 2304 + 768 + h * 64 + qd * 8;
    bf16x8 kd00 = *(const bf16x8*)kd;
    bf16x8 kd01 = *(const bf16x8*)(kd + 32);
    bf16x8 kd10 = *(const bf16x8*)(kd + (long)16 * 2304);
    bf16x8 kd11 = *(const bf16x8*)(kd + (long)16 * 2304 + 32);
    float part0 = 0.f, part1 = 0.f;
#pragma unroll
    for (int jj = 0; jj < 8; jj++) {
      part0 += (float)qf00[jj] * (float)kd00[jj] + (float)qf01[jj] * (float)kd01[jj];
      part1 += (float)qf10[jj] * (float)kd10[jj] + (float)qf11[jj] * (float)kd11[jj];
    }
    part0 += __shfl_xor(part0, 16); part0 += __shfl_xor(part0, 32);
    part1 += __shfl_xor(part1, 16); part1 += __shfl_xor(part1, 32);
    const float p0 = policy[b * 1024 + q0 + l15];
    const float p1 = policy[b * 1024 + q0 + 16 + l15];
    if (qd == 0) {
      sD[wave][l15] = fexp2(part0) * (1.0f - p0);
      sD[wave][16 + l15] = fexp2(part1) * (1.0f - p1);
    }
    __builtin_amdgcn_s_waitcnt(0);
    const unsigned short* vdiag = qkv + (long)(b * 1024 + q0) * 2304 + 1536 + h * 64 + l15;
#pragma unroll
    for (int r = 0; r < 4; r++) {
      const int row = qd * 4 + r;
      const float c0v = sD[wave][row], c1v = sD[wave][16 + row];
#pragma unroll
      for (int j = 0; j < 4; j++) {
        O0[j][r] += c0v * bf2f(vdiag[(long)row * 2304 + j * 16]);
        O1[j][r] += c1v * bf2f(vdiag[(long)(16 + row) * 2304 + j * 16]);
      }
      Dl0[r] += c0v;
      Dl1[r] += c1v;
    }
  }
  const long ob = (long)(b * 1024 + q0 + qd * 4) * 768 + h * 64 + l15;
#pragma unroll
  for (int r = 0; r < 4; r++) {
    const float li0 = 1.0f / (Dl0[r] + EPSF);
    const float li1 = 1.0f / (Dl1[r] + EPSF);
#pragma unroll
    for (int j = 0; j < 4; j++) {
      aout[ob + (long)r * 768 + j * 16] = f2bf(O0[j][r] * li0);
      aout[ob + (long)(16 * 768) + r * 768 + j * 16] = f2bf(O1[j][r] * li1);
    }
  }
}

extern "C" void kernel_launch(void* const* d_in, const int* in_sizes, int n_in,
                              void* d_out, int out_size, void* d_ws, size_t ws_size,
                              hipStream_t stream) {
  const float* x      = (const float*)d_in[0];   // [8,1024,768]
  const float* policy = (const float*)d_in[1];   // [8,1024,1]
  const float* qkv_w  = (const float*)d_in[2];   // [2304,768]
  const float* proj_w = (const float*)d_in[3];   // [768,768]
  const float* proj_b = (const float*)d_in[4];   // [768]
  float* out = (float*)d_out;                    // [8,1024,768] fp32

  char* ws = (char*)d_ws;
  unsigned short* xb    = (unsigned short*)(ws + 0);         // 12,582,912 B
  unsigned short* wqkv  = (unsigned short*)(ws + 12582912);  //  3,538,944 B
  unsigned short* wproj = (unsigned short*)(ws + 16121856);  //  1,179,648 B
  unsigned short* qkvb  = (unsigned short*)(ws + 17301504);  // 37,748,736 B
  unsigned short* vTp   = (unsigned short*)(ws + 55050240);  // 12,582,912 B
  unsigned short* aoutb = (unsigned short*)(ws + 67633152);  // 12,582,912 B
  unsigned short* pbf   = (unsigned short*)(ws + 80216064);  //     16,384 B

  prep_kernel<<<4256, 256, 0, stream>>>(x, qkv_w, proj_w, policy, xb, wqkv, wproj, pbf);
  gemm_bt<0, 128, 4><<<dim3(18 * 64), 256, 0, stream>>>(xb, wqkv, qkvb, nullptr, 8192, 2304, 768);
  transpose_v<<<dim3(16, 96), 256, 0, stream>>>(qkvb, policy, vTp);
  attn_kernel<<<dim3(768), 256, 0, stream>>>(qkvb, vTp, pbf, policy, aoutb);
  gemm_bt<1, 64, 3><<<dim3(12 * 64), 256, 0, stream>>>(aoutb, wproj, out, proj_b, 8192, 768, 768);
}

// Round 8
// 177.332 us; speedup vs baseline: 1.0293x; 1.0018x over previous
//
#include <hip/hip_runtime.h>

typedef __bf16 bf16x8 __attribute__((ext_vector_type(8)));
typedef float floatx4 __attribute__((ext_vector_type(4)));

#define EPSF 1e-6f

__device__ inline unsigned short f2bf(float f) {  // RNE
  union { float f; unsigned u; } x; x.f = f;
  unsigned r = x.u + 0x7FFFu + ((x.u >> 16) & 1u);
  return (unsigned short)(r >> 16);
}
__device__ inline float bf2f(unsigned short u) {
  union { unsigned u; float f; } x; x.u = ((unsigned)u) << 16;
  return x.f;
}
// pack two f32 -> bf16x2 dword, round-half-up (prep/gemm epilogue path)
__device__ inline unsigned pk2bf(float lo, float hi) {
  union { float f; unsigned u; } a, b; a.f = lo; b.f = hi;
  unsigned ua = a.u + 0x8000u, ub = b.u + 0x8000u;
  return (ub & 0xFFFF0000u) | (ua >> 16);
}
// HW packed f32x2 -> bf16x2 (RNE) — single VALU instr, no builtin on gfx950 (T12/m240)
__device__ inline unsigned cvtpk(float lo, float hi) {
  unsigned r;
  asm("v_cvt_pk_bf16_f32 %0, %1, %2" : "=v"(r) : "v"(lo), "v"(hi));
  return r;
}
// single-instruction v_exp_f32 (input in log2 domain — scale folded into Q weights)
__device__ inline float fexp2(float x) { return __builtin_amdgcn_exp2f(x); }

__device__ inline floatx4 mfma16(bf16x8 a, bf16x8 b, floatx4 c) {
  return __builtin_amdgcn_mfma_f32_16x16x32_bf16(a, b, c, 0, 0, 0);
}

__device__ inline void gll16(const unsigned short* g, unsigned short* l) {
  __builtin_amdgcn_global_load_lds((__attribute__((address_space(1))) void*)g,
                                   (__attribute__((address_space(3))) void*)l, 16, 0, 0);
}

// ctx permutation sigma^-1 (PV k-dim): stored pos p in a 32-chunk holds original ctx c
__device__ __host__ inline int sigma_inv(int p) {
  const int qq = p >> 3, jj = p & 7;
  return (jj < 4) ? (qq * 4 + jj) : (16 + qq * 4 + jj - 4);
}

// ---------- merged prep: x cast | qkv_w cast (Q-scaled) | proj_w cast with k-dim gather-perm | policy pack ----------
// feature perm pi(c) = 4*(c%16) + c/16 within each 64-block (qkv GEMM packed epilogue)
__global__ __launch_bounds__(256) void prep_kernel(const float* __restrict__ x,
                                                   const float* __restrict__ qkv_w,
                                                   const float* __restrict__ proj_w,
                                                   const float* __restrict__ policy,
                                                   unsigned short* __restrict__ xb,
                                                   unsigned short* __restrict__ wqkv,
                                                   unsigned short* __restrict__ wproj,
                                                   unsigned short* __restrict__ pbf) {
  const int bid = blockIdx.x, tid = threadIdx.x;
  if (bid < 3072) {  // x cast: 6291456 elems
    const int i = bid * 2048 + tid * 8;
    float4 v0 = *(const float4*)(x + i);
    float4 v1 = *(const float4*)(x + i + 4);
    __align__(16) unsigned short o[8] = {f2bf(v0.x), f2bf(v0.y), f2bf(v0.z), f2bf(v0.w),
                                         f2bf(v1.x), f2bf(v1.y), f2bf(v1.z), f2bf(v1.w)};
    *(float4*)(xb + i) = *(float4*)o;
  } else if (bid < 3936) {  // qkv_w cast: 1769472 elems, first 589824 (Q rows) * 0.125*log2(e)
    const int i = (bid - 3072) * 2048 + tid * 8;
    const float s = (i < 589824) ? 0.18033688011112042f : 1.0f;
    float4 v0 = *(const float4*)(qkv_w + i);
    float4 v1 = *(const float4*)(qkv_w + i + 4);
    __align__(16) unsigned short o[8] = {
        f2bf(v0.x * s), f2bf(v0.y * s), f2bf(v0.z * s), f2bf(v0.w * s),
        f2bf(v1.x * s), f2bf(v1.y * s), f2bf(v1.z * s), f2bf(v1.w * s)};
    *(float4*)(wqkv + i) = *(float4*)o;
  } else if (bid < 4224) {  // proj_w cast with in-dim pi perm: 589824 elems
    const int i0 = (bid - 3936) * 2048 + tid * 8;  // dest index (row-contig)
    const int base = (i0 / 768) * 768 + ((i0 % 768) & ~63);
    __align__(16) unsigned short o[8];
#pragma unroll
    for (int t = 0; t < 8; t++) {
      const int cp = (i0 + t) & 63;                 // stored position within 64-block
      const int c = 16 * (cp & 3) + (cp >> 2);      // original column
      o[t] = f2bf(proj_w[base + c]);
    }
    *(float4*)(wproj + i0) = *(float4*)o;
  } else {  // policy pack: 8192 elems, ctx-perm sigma per 32-chunk
    const int idx = (bid - 4224) * 256 + tid;
    const int b = idx >> 10, g = idx & 1023;
    const int c = ((g >> 5) << 5) + sigma_inv(g & 31);
    pbf[idx] = f2bf(policy[b * 1024 + c]);
  }
}

// ---------- bf16 GEMM: BK=64, XOR-8 swizzle, XCD y-band grid swizzle for L2 locality ----------
// 1D grid; y = (bid&7)*8 + ((bid>>3)&7), x = bid>>6 — XCD k touches one 1024-row A band.
// EP=0 (BN=128): bf16 out with 64-block col-perm pi (packed dwordx2 stores).
// EP=1 (BN=64): f32 out + bias, natural layout.  W = min waves/EU.
template <int EP, int BN, int W>
__global__ __launch_bounds__(256, W) void gemm_bt(const unsigned short* __restrict__ A,
                                                  const unsigned short* __restrict__ Bt,
                                                  void* __restrict__ Cout,
                                                  const float* __restrict__ bias,
                                                  int M, int N, int K) {
  constexpr int J = BN / 32;
  __shared__ __align__(16) unsigned short sA[128 * 64];
  __shared__ __align__(16) unsigned short sB[BN * 64];
  const int bid = blockIdx.x;
  const int yb = (bid & 7) * 8 + ((bid >> 3) & 7);
  const int xb_ = bid >> 6;
  const int m0 = yb * 128, n0 = xb_ * BN;
  const int tid = threadIdx.x;
  const int lane = tid & 63, wave = tid >> 6;
  const int qd = lane >> 4, l15 = lane & 15;
  const int wr = (wave >> 1) * 64, wc = (wave & 1) * (BN / 2);
  const int srow = tid >> 3;
  const int scb = (tid & 7) ^ (srow & 7);
  const unsigned short* Ag = A + (long)(m0 + srow) * K + scb * 8;
  const unsigned short* Bg = Bt + (long)(n0 + srow) * K + scb * 8;
  const int x7 = l15 & 7;
  floatx4 acc[4][J] = {};
  for (int k0 = 0; k0 < K; k0 += 64) {
    __syncthreads();
#pragma unroll
    for (int p = 0; p < 4; p++) gll16(Ag + (long)(p * 32) * K + k0, sA + p * 2048 + wave * 512);
#pragma unroll
    for (int p = 0; p < J; p++) gll16(Bg + (long)(p * 32) * K + k0, sB + p * 2048 + wave * 512);
    __syncthreads();
#pragma unroll
    for (int s = 0; s < 2; s++) {
      const int cw = ((s * 4 + qd) ^ x7) * 8;
      bf16x8 af[4], bf[J];
#pragma unroll
      for (int i = 0; i < 4; i++) af[i] = *(const bf16x8*)&sA[(wr + i * 16 + l15) * 64 + cw];
#pragma unroll
      for (int j = 0; j < J; j++) bf[j] = *(const bf16x8*)&sB[(wc + j * 16 + l15) * 64 + cw];
#pragma unroll
      for (int i = 0; i < 4; i++)
#pragma unroll
        for (int j = 0; j < J; j++) acc[i][j] = mfma16(af[i], bf[j], acc[i][j]);
    }
  }
  if constexpr (EP == 0) {
    // feature f = wc + 16j + l15 stored at col' = wc + 4*l15 + j  (pi within 64-block)
#pragma unroll
    for (int i = 0; i < 4; i++)
#pragma unroll
      for (int r = 0; r < 4; r++) {
        const int row = m0 + wr + i * 16 + qd * 4 + r;
        __align__(8) unsigned short pk[4];
#pragma unroll
        for (int j = 0; j < 4; j++) pk[j] = f2bf(acc[i][j][r]);
        *(uint2*)((unsigned short*)Cout + (long)row * N + n0 + wc + 4 * l15) = *(uint2*)pk;
      }
  } else {
#pragma unroll
    for (int i = 0; i < 4; i++)
#pragma unroll
      for (int j = 0; j < J; j++) {
        const int col = n0 + wc + j * 16 + l15;
#pragma unroll
        for (int r = 0; r < 4; r++) {
          const int row = m0 + wr + i * 16 + qd * 4 + r;
          ((float*)Cout)[(long)row * N + col] = acc[i][j][r] + bias[col];
        }
      }
  }
}

// ---------- V transpose + policy fold + ctx sigma-perm ----------
__global__ __launch_bounds__(256) void transpose_v(const unsigned short* __restrict__ qkv,
                                                   const float* __restrict__ policy,
                                                   unsigned short* __restrict__ vTp) {
  __shared__ unsigned short tile[64][72];
  __shared__ float sPol[64];
  const int bh = blockIdx.y;
  const int b = bh / 12, h = bh % 12;
  const int n0 = blockIdx.x * 64;
  const int t = threadIdx.x;
  if (t < 64) sPol[t] = policy[b * 1024 + n0 + t];
  {
    const int nr = t >> 2, dc = (t & 3) * 16;
    const unsigned short* src = qkv + (long)(b * 1024 + n0 + nr) * 2304 + 2 * 768 + h * 64 + dc;
    float4 v0 = *(const float4*)src;
    float4 v1 = *(const float4*)(src + 8);
    *(float4*)&tile[nr][dc] = v0;
    *(float4*)&tile[nr][dc + 8] = v1;
  }
  __syncthreads();
  {
    const int d = t >> 2, nc = (t & 3) * 16;
    __align__(16) unsigned short o[16];
#pragma unroll
    for (int jj = 0; jj < 16; jj++) {
      const int cc = nc + jj;
      const int cl = (cc & 32) + sigma_inv(cc & 31);
      o[jj] = f2bf(bf2f(tile[cl][d]) * sPol[cl]);
    }
    unsigned short* dst = vTp + (long)(bh * 64 + d) * 1024 + n0 + nc;
    *(float4*)dst = *(float4*)&o[0];
    *(float4*)(dst + 8) = *(float4*)&o[8];
  }
}

// ---------- attention v18 (BANKED BEST): reg-K prefetch + ping-pong unroll + cvt_pk ----------
// History: v8 42us | v12 100us FAIL (reg-direct K/V uncoalesced; LDS staging IS the coalescer) |
//   v13/v14 NULL (counted-vmcnt sync axis dead — DMA latency was never exposed, ~2 iters slack) |
//   v16 41.0 WIN (reg-K prefetch kills post-barrier LDS latency head; raw barrier + vmcnt(2)) |
//   v17 51.5 FAIL (64q/wave: LDS traffic halved as predicted — conflicts 1.57M->786K — but
//     6 waves/CU starves TLP; pipes stop overlapping) |
//   v18 <41.1 WIN (ping-pong unroll removes 16 v_mov/iter; v_cvt_pk_bf16_f32 packing) |
//   v19 CORRECTNESS FAIL (V-reg-prefetch across barrier: absmax 0.158; race not identifiable
//     on paper — AXIS CLOSED: K-only register prefetch is the verified-safe depth).
// Remaining headroom (~15%): exp dependency chain + barrier convoy at 12 waves/CU; would need
//   32x32-MFMA restructure. Profiler blind below ~41us (harness fills occupy top-5).
__global__ __launch_bounds__(256, 3) void attn_kernel(const unsigned short* __restrict__ qkv,
                                                      const unsigned short* __restrict__ vTp,
                                                      const unsigned short* __restrict__ pbf,
                                                      const float* __restrict__ policy,
                                                      unsigned short* __restrict__ aout) {
  __shared__ __align__(16) unsigned short sK[4][2048];  // 32 ctx x 64 d, slot cb = c ^ (row&7)
  __shared__ __align__(16) unsigned short sV[4][2048];  // 64 d x 32 ctx, slot cb = c ^ ((d^(d>>2))&3)
  __shared__ __align__(16) unsigned short sPv[1024];
  __shared__ float sD[4][32];
  const int bid = blockIdx.x;
  const int bh = bid % 96, qt = bid / 96;  // bh-fast for XCD L2 locality
  const int b = bh / 12, h = bh % 12;
  const int tid = threadIdx.x;
  const int wave = tid >> 6, lane = tid & 63;
  const int qd = lane >> 4, l15 = lane & 15;
  const int q0 = qt * 128 + wave * 32;
  const unsigned short* qb = qkv + (long)(b * 1024 + q0 + l15) * 2304 + h * 64 + qd * 8;
  bf16x8 qf00 = *(const bf16x8*)qb;  // Q pre-scaled by 0.125*log2e
  bf16x8 qf01 = *(const bf16x8*)(qb + 32);
  bf16x8 qf10 = *(const bf16x8*)(qb + (long)16 * 2304);
  bf16x8 qf11 = *(const bf16x8*)(qb + (long)16 * 2304 + 32);
  if (tid < 128) *(float4*)(sPv + tid * 8) = *(const float4*)(pbf + b * 1024 + tid * 8);
  const int krow = wave * 8 + (lane >> 3);
  const int kcb = (lane & 7) ^ (lane >> 3);
  const unsigned short* kgl = qkv + (long)(b * 1024 + krow) * 2304 + 768 + h * 64 + kcb * 8;
  const int vrow = tid >> 2;
  const int vcb = (tid & 3) ^ ((vrow ^ (vrow >> 2)) & 3);
  const unsigned short* vgl = vTp + (long)(bh * 64 + vrow) * 1024 + vcb * 8;
  const int x7 = l15 & 7;
  const int vsw = (qd ^ ((l15 ^ (l15 >> 2)) & 3)) * 8;
  floatx4 O0[4] = {}, O1[4] = {};
  floatx4 Dl0 = {}, Dl1 = {};
  const floatx4 z = {0.f, 0.f, 0.f, 0.f};
  // prologue: stage chunks 0..2 (3-deep); vmcnt(2) => chunks 0,1 landed, chunk 2 in flight
#pragma unroll
  for (int c = 0; c < 3; ++c) {
    gll16(kgl + (long)(32 * c) * 2304, &sK[c][wave * 512]);
    gll16(vgl + 32 * c, &sV[c][wave * 512]);
  }
  asm volatile("s_waitcnt vmcnt(2) lgkmcnt(0)" ::: "memory");
  __builtin_amdgcn_s_barrier();
  asm volatile("" ::: "memory");
  // preload K[0] fragments into register set A
  bf16x8 kA00 = *(const bf16x8*)&sK[0][(0 + l15) * 64 + ((0 + qd) ^ x7) * 8];
  bf16x8 kA01 = *(const bf16x8*)&sK[0][(0 + l15) * 64 + ((4 + qd) ^ x7) * 8];
  bf16x8 kA10 = *(const bf16x8*)&sK[0][(16 + l15) * 64 + ((0 + qd) ^ x7) * 8];
  bf16x8 kA11 = *(const bf16x8*)&sK[0][(16 + l15) * 64 + ((4 + qd) ^ x7) * 8];
  bf16x8 kB00, kB01, kB10, kB11;
  // one iteration body: consumes frag set "c", prefetches next chunk's frags into set "n"
  auto body = [&](int it, bf16x8& c00, bf16x8& c01, bf16x8& c10, bf16x8& c11,
                  bf16x8& n00, bf16x8& n01, bf16x8& n10, bf16x8& n11) {
    const int buf = it & 3;
    if (it < 29) {  // stage chunk it+3 into buf (it+3)&3 (reads of that buf done pre-barrier)
      const long co = (long)(32 * (it + 3));
      gll16(kgl + co * 2304, &sK[(it + 3) & 3][wave * 512]);
      gll16(vgl + co, &sV[(it + 3) & 3][wave * 512]);
    }
    const int c0 = it * 32;
    bf16x8 pv = *(const bf16x8*)&sPv[c0 + qd * 8];
    // S^T = K·Q^T from REGISTER K — issues immediately after barrier, no LDS head
    __builtin_amdgcn_s_setprio(1);
    floatx4 tA0 = mfma16(c01, qf01, mfma16(c00, qf00, z));
    floatx4 tB0 = mfma16(c11, qf01, mfma16(c10, qf00, z));
    floatx4 tA1 = mfma16(c01, qf11, mfma16(c00, qf10, z));
    floatx4 tB1 = mfma16(c11, qf11, mfma16(c10, qf10, z));
    __builtin_amdgcn_s_setprio(0);
    // prefetch next chunk's K frags (chunk it+1 landed by prev barrier) — retires under exp/pack
    const int nb = (it + 1) & 3;  // at it=31 reads stale buf 0: values dead, no hazard
    n00 = *(const bf16x8*)&sK[nb][(0 + l15) * 64 + ((0 + qd) ^ x7) * 8];
    n01 = *(const bf16x8*)&sK[nb][(0 + l15) * 64 + ((4 + qd) ^ x7) * 8];
    n10 = *(const bf16x8*)&sK[nb][(16 + l15) * 64 + ((0 + qd) ^ x7) * 8];
    n11 = *(const bf16x8*)&sK[nb][(16 + l15) * 64 + ((4 + qd) ^ x7) * 8];
    uint4 pu0, pu1;
    pu0.x = cvtpk(fexp2(tA0[0]), fexp2(tA0[1]));
    pu0.y = cvtpk(fexp2(tA0[2]), fexp2(tA0[3]));
    pu0.z = cvtpk(fexp2(tB0[0]), fexp2(tB0[1]));
    pu0.w = cvtpk(fexp2(tB0[2]), fexp2(tB0[3]));
    pu1.x = cvtpk(fexp2(tA1[0]), fexp2(tA1[1]));
    pu1.y = cvtpk(fexp2(tA1[2]), fexp2(tA1[3]));
    pu1.z = cvtpk(fexp2(tB1[0]), fexp2(tB1[1]));
    pu1.w = cvtpk(fexp2(tB1[2]), fexp2(tB1[3]));
    bf16x8 pf0 = *(bf16x8*)&pu0;
    bf16x8 pf1 = *(bf16x8*)&pu1;
    bf16x8 vf0 = *(const bf16x8*)&sV[buf][(0 * 16 + l15) * 32 + vsw];
    bf16x8 vf1 = *(const bf16x8*)&sV[buf][(1 * 16 + l15) * 32 + vsw];
    bf16x8 vf2 = *(const bf16x8*)&sV[buf][(2 * 16 + l15) * 32 + vsw];
    bf16x8 vf3 = *(const bf16x8*)&sV[buf][(3 * 16 + l15) * 32 + vsw];
    __builtin_amdgcn_s_setprio(1);
    Dl0 = mfma16(pf0, pv, Dl0);
    Dl1 = mfma16(pf1, pv, Dl1);
    O0[0] = mfma16(pf0, vf0, O0[0]); O1[0] = mfma16(pf1, vf0, O1[0]);
    O0[1] = mfma16(pf0, vf1, O0[1]); O1[1] = mfma16(pf1, vf1, O1[1]);
    O0[2] = mfma16(pf0, vf2, O0[2]); O1[2] = mfma16(pf1, vf2, O1[2]);
    O0[3] = mfma16(pf0, vf3, O0[3]); O1[3] = mfma16(pf1, vf3, O1[3]);
    __builtin_amdgcn_s_setprio(0);
    // counted wait: retire chunk it+2 (needed next iter for reg-prefetch); newest 2 stay in flight
    if (it < 29) asm volatile("s_waitcnt vmcnt(2)" ::: "memory");
    else         asm volatile("s_waitcnt vmcnt(0)" ::: "memory");
    __builtin_amdgcn_s_barrier();
    asm volatile("" ::: "memory");
  };
  // 2x-unrolled ping-pong: even iters consume set A / fill set B; odd consume B / fill A.
#pragma unroll 1
  for (int itp = 0; itp < 16; ++itp) {
    body(2 * itp,     kA00, kA01, kA10, kA11, kB00, kB01, kB10, kB11);
    body(2 * itp + 1, kB00, kB01, kB10, kB11, kA00, kA01, kA10, kA11);
  }
  // ---- diagonal correction: O[q] += e_qq(1-p_q) V[q]; l_q += e_qq(1-p_q) ----
  {
    const unsigned short* kd = qkv + (long)(b * 1024 + q0 + l15) * 2304 + 768 + h * 64 + qd * 8;
    bf16x8 kd00 = *(const bf16x8*)kd;
    bf16x8 kd01 = *(const bf16x8*)(kd + 32);
    bf16x8 kd10 = *(const bf16x8*)(kd + (long)16 * 2304);
    bf16x8 kd11 = *(const bf16x8*)(kd + (long)16 * 2304 + 32);
    float part0 = 0.f, part1 = 0.f;
#pragma unroll
    for (int jj = 0; jj < 8; jj++) {
      part0 += (float)qf00[jj] * (float)kd00[jj] + (float)qf01[jj] * (float)kd01[jj];
      part1 += (float)qf10[jj] * (float)kd10[jj] + (float)qf11[jj] * (float)kd11[jj];
    }
    part0 += __shfl_xor(part0, 16); part0 += __shfl_xor(part0, 32);
    part1 += __shfl_xor(part1, 16); part1 += __shfl_xor(part1, 32);
    const float p0 = policy[b * 1024 + q0 + l15];
    const float p1 = policy[b * 1024 + q0 + 16 + l15];
    if (qd == 0) {
      sD[wave][l15] = fexp2(part0) * (1.0f - p0);
      sD[wave][16 + l15] = fexp2(part1) * (1.0f - p1);
    }
    __builtin_amdgcn_s_waitcnt(0);
    const unsigned short* vdiag = qkv + (long)(b * 1024 + q0) * 2304 + 1536 + h * 64 + l15;
#pragma unroll
    for (int r = 0; r < 4; r++) {
      const int row = qd * 4 + r;
      const float c0v = sD[wave][row], c1v = sD[wave][16 + row];
#pragma unroll
      for (int j = 0; j < 4; j++) {
        O0[j][r] += c0v * bf2f(vdiag[(long)row * 2304 + j * 16]);
        O1[j][r] += c1v * bf2f(vdiag[(long)(16 + row) * 2304 + j * 16]);
      }
      Dl0[r] += c0v;
      Dl1[r] += c1v;
    }
  }
  const long ob = (long)(b * 1024 + q0 + qd * 4) * 768 + h * 64 + l15;
#pragma unroll
  for (int r = 0; r < 4; r++) {
    const float li0 = 1.0f / (Dl0[r] + EPSF);
    const float li1 = 1.0f / (Dl1[r] + EPSF);
#pragma unroll
    for (int j = 0; j < 4; j++) {
      aout[ob + (long)r * 768 + j * 16] = f2bf(O0[j][r] * li0);
      aout[ob + (long)(16 * 768) + r * 768 + j * 16] = f2bf(O1[j][r] * li1);
    }
  }
}

extern "C" void kernel_launch(void* const* d_in, const int* in_sizes, int n_in,
                              void* d_out, int out_size, void* d_ws, size_t ws_size,
                              hipStream_t stream) {
  const float* x      = (const float*)d_in[0];   // [8,1024,768]
  const float* policy = (const float*)d_in[1];   // [8,1024,1]
  const float* qkv_w  = (const float*)d_in[2];   // [2304,768]
  const float* proj_w = (const float*)d_in[3];   // [768,768]
  const float* proj_b = (const float*)d_in[4];   // [768]
  float* out = (float*)d_out;                    // [8,1024,768] fp32

  char* ws = (char*)d_ws;
  unsigned short* xb    = (unsigned short*)(ws + 0);         // 12,582,912 B
  unsigned short* wqkv  = (unsigned short*)(ws + 12582912);  //  3,538,944 B
  unsigned short* wproj = (unsigned short*)(ws + 16121856);  //  1,179,648 B
  unsigned short* qkvb  = (unsigned short*)(ws + 17301504);  // 37,748,736 B
  unsigned short* vTp   = (unsigned short*)(ws + 55050240);  // 12,582,912 B
  unsigned short* aoutb = (unsigned short*)(ws + 67633152);  // 12,582,912 B
  unsigned short* pbf   = (unsigned short*)(ws + 80216064);  //     16,384 B

  prep_kernel<<<4256, 256, 0, stream>>>(x, qkv_w, proj_w, policy, xb, wqkv, wproj, pbf);
  gemm_bt<0, 128, 4><<<dim3(18 * 64), 256, 0, stream>>>(xb, wqkv, qkvb, nullptr, 8192, 2304, 768);
  transpose_v<<<dim3(16, 96), 256, 0, stream>>>(qkvb, policy, vTp);
  attn_kernel<<<dim3(768), 256, 0, stream>>>(qkvb, vTp, pbf, policy, aoutb);
  gemm_bt<1, 64, 3><<<dim3(12 * 64), 256, 0, stream>>>(aoutb, wproj, out, proj_b, 8192, 768, 768);
}

// Round 9
// 175.497 us; speedup vs baseline: 1.0400x; 1.0105x over previous
//
#include <hip/hip_runtime.h>

typedef __bf16 bf16x8 __attribute__((ext_vector_type(8)));
typedef float floatx4 __attribute__((ext_vector_type(4)));

#define EPSF 1e-6f

__device__ inline unsigned short f2bf(float f) {  // RNE
  union { float f; unsigned u; } x; x.f = f;
  unsigned r = x.u + 0x7FFFu + ((x.u >> 16) & 1u);
  return (unsigned short)(r >> 16);
}
__device__ inline float bf2f(unsigned short u) {
  union { unsigned u; float f; } x; x.u = ((unsigned)u) << 16;
  return x.f;
}
// pack two f32 -> bf16x2 dword, round-half-up (prep/gemm epilogue path)
__device__ inline unsigned pk2bf(float lo, float hi) {
  union { float f; unsigned u; } a, b; a.f = lo; b.f = hi;
  unsigned ua = a.u + 0x8000u, ub = b.u + 0x8000u;
  return (ub & 0xFFFF0000u) | (ua >> 16);
}
// HW packed f32x2 -> bf16x2 (RNE) — single VALU instr, no builtin on gfx950 (T12/m240)
__device__ inline unsigned cvtpk(float lo, float hi) {
  unsigned r;
  asm("v_cvt_pk_bf16_f32 %0, %1, %2" : "=v"(r) : "v"(lo), "v"(hi));
  return r;
}
// single-instruction v_exp_f32 (input in log2 domain — scale folded into Q weights)
__device__ inline float fexp2(float x) { return __builtin_amdgcn_exp2f(x); }

__device__ inline floatx4 mfma16(bf16x8 a, bf16x8 b, floatx4 c) {
  return __builtin_amdgcn_mfma_f32_16x16x32_bf16(a, b, c, 0, 0, 0);
}

__device__ inline void gll16(const unsigned short* g, unsigned short* l) {
  __builtin_amdgcn_global_load_lds((__attribute__((address_space(1))) void*)g,
                                   (__attribute__((address_space(3))) void*)l, 16, 0, 0);
}

// ctx permutation sigma^-1 (PV k-dim): stored pos p in a 32-chunk holds original ctx c
__device__ __host__ inline int sigma_inv(int p) {
  const int qq = p >> 3, jj = p & 7;
  return (jj < 4) ? (qq * 4 + jj) : (16 + qq * 4 + jj - 4);
}

// ---------- merged prep: x cast | qkv_w cast (Q-scaled) | proj_w cast with k-dim gather-perm | policy pack ----------
// feature perm pi(c) = 4*(c%16) + c/16 within each 64-block (qkv GEMM packed epilogue)
__global__ __launch_bounds__(256) void prep_kernel(const float* __restrict__ x,
                                                   const float* __restrict__ qkv_w,
                                                   const float* __restrict__ proj_w,
                                                   const float* __restrict__ policy,
                                                   unsigned short* __restrict__ xb,
                                                   unsigned short* __restrict__ wqkv,
                                                   unsigned short* __restrict__ wproj,
                                                   unsigned short* __restrict__ pbf) {
  const int bid = blockIdx.x, tid = threadIdx.x;
  if (bid < 3072) {  // x cast: 6291456 elems
    const int i = bid * 2048 + tid * 8;
    float4 v0 = *(const float4*)(x + i);
    float4 v1 = *(const float4*)(x + i + 4);
    __align__(16) unsigned short o[8] = {f2bf(v0.x), f2bf(v0.y), f2bf(v0.z), f2bf(v0.w),
                                         f2bf(v1.x), f2bf(v1.y), f2bf(v1.z), f2bf(v1.w)};
    *(float4*)(xb + i) = *(float4*)o;
  } else if (bid < 3936) {  // qkv_w cast: 1769472 elems, first 589824 (Q rows) * 0.125*log2(e)
    const int i = (bid - 3072) * 2048 + tid * 8;
    const float s = (i < 589824) ? 0.18033688011112042f : 1.0f;
    float4 v0 = *(const float4*)(qkv_w + i);
    float4 v1 = *(const float4*)(qkv_w + i + 4);
    __align__(16) unsigned short o[8] = {
        f2bf(v0.x * s), f2bf(v0.y * s), f2bf(v0.z * s), f2bf(v0.w * s),
        f2bf(v1.x * s), f2bf(v1.y * s), f2bf(v1.z * s), f2bf(v1.w * s)};
    *(float4*)(wqkv + i) = *(float4*)o;
  } else if (bid < 4224) {  // proj_w cast with in-dim pi perm: 589824 elems
    const int i0 = (bid - 3936) * 2048 + tid * 8;  // dest index (row-contig)
    const int base = (i0 / 768) * 768 + ((i0 % 768) & ~63);
    __align__(16) unsigned short o[8];
#pragma unroll
    for (int t = 0; t < 8; t++) {
      const int cp = (i0 + t) & 63;                 // stored position within 64-block
      const int c = 16 * (cp & 3) + (cp >> 2);      // original column
      o[t] = f2bf(proj_w[base + c]);
    }
    *(float4*)(wproj + i0) = *(float4*)o;
  } else {  // policy pack: 8192 elems, ctx-perm sigma per 32-chunk
    const int idx = (bid - 4224) * 256 + tid;
    const int b = idx >> 10, g = idx & 1023;
    const int c = ((g >> 5) << 5) + sigma_inv(g & 31);
    pbf[idx] = f2bf(policy[b * 1024 + c]);
  }
}

// ---------- bf16 GEMM: BK=64, XOR-8 swizzle, XCD y-band grid swizzle for L2 locality ----------
// 1D grid; y = (bid&7)*8 + ((bid>>3)&7), x = bid>>6 — XCD k touches one 1024-row A band.
// EP=0 (BN=128): bf16 out with 64-block col-perm pi (packed dwordx2 stores).
// EP=1 (BN=64): f32 out + bias, natural layout.  W = min waves/EU.
template <int EP, int BN, int W>
__global__ __launch_bounds__(256, W) void gemm_bt(const unsigned short* __restrict__ A,
                                                  const unsigned short* __restrict__ Bt,
                                                  void* __restrict__ Cout,
                                                  const float* __restrict__ bias,
                                                  int M, int N, int K) {
  constexpr int J = BN / 32;
  __shared__ __align__(16) unsigned short sA[128 * 64];
  __shared__ __align__(16) unsigned short sB[BN * 64];
  const int bid = blockIdx.x;
  const int yb = (bid & 7) * 8 + ((bid >> 3) & 7);
  const int xb_ = bid >> 6;
  const int m0 = yb * 128, n0 = xb_ * BN;
  const int tid = threadIdx.x;
  const int lane = tid & 63, wave = tid >> 6;
  const int qd = lane >> 4, l15 = lane & 15;
  const int wr = (wave >> 1) * 64, wc = (wave & 1) * (BN / 2);
  const int srow = tid >> 3;
  const int scb = (tid & 7) ^ (srow & 7);
  const unsigned short* Ag = A + (long)(m0 + srow) * K + scb * 8;
  const unsigned short* Bg = Bt + (long)(n0 + srow) * K + scb * 8;
  const int x7 = l15 & 7;
  floatx4 acc[4][J] = {};
  for (int k0 = 0; k0 < K; k0 += 64) {
    __syncthreads();
#pragma unroll
    for (int p = 0; p < 4; p++) gll16(Ag + (long)(p * 32) * K + k0, sA + p * 2048 + wave * 512);
#pragma unroll
    for (int p = 0; p < J; p++) gll16(Bg + (long)(p * 32) * K + k0, sB + p * 2048 + wave * 512);
    __syncthreads();
#pragma unroll
    for (int s = 0; s < 2; s++) {
      const int cw = ((s * 4 + qd) ^ x7) * 8;
      bf16x8 af[4], bf[J];
#pragma unroll
      for (int i = 0; i < 4; i++) af[i] = *(const bf16x8*)&sA[(wr + i * 16 + l15) * 64 + cw];
#pragma unroll
      for (int j = 0; j < J; j++) bf[j] = *(const bf16x8*)&sB[(wc + j * 16 + l15) * 64 + cw];
#pragma unroll
      for (int i = 0; i < 4; i++)
#pragma unroll
        for (int j = 0; j < J; j++) acc[i][j] = mfma16(af[i], bf[j], acc[i][j]);
    }
  }
  if constexpr (EP == 0) {
    // feature f = wc + 16j + l15 stored at col' = wc + 4*l15 + j  (pi within 64-block)
#pragma unroll
    for (int i = 0; i < 4; i++)
#pragma unroll
      for (int r = 0; r < 4; r++) {
        const int row = m0 + wr + i * 16 + qd * 4 + r;
        __align__(8) unsigned short pk[4];
#pragma unroll
        for (int j = 0; j < 4; j++) pk[j] = f2bf(acc[i][j][r]);
        *(uint2*)((unsigned short*)Cout + (long)row * N + n0 + wc + 4 * l15) = *(uint2*)pk;
      }
  } else {
#pragma unroll
    for (int i = 0; i < 4; i++)
#pragma unroll
      for (int j = 0; j < J; j++) {
        const int col = n0 + wc + j * 16 + l15;
#pragma unroll
        for (int r = 0; r < 4; r++) {
          const int row = m0 + wr + i * 16 + qd * 4 + r;
          ((float*)Cout)[(long)row * N + col] = acc[i][j][r] + bias[col];
        }
      }
  }
}

// ---------- V transpose + policy fold + ctx sigma-perm ----------
__global__ __launch_bounds__(256) void transpose_v(const unsigned short* __restrict__ qkv,
                                                   const float* __restrict__ policy,
                                                   unsigned short* __restrict__ vTp) {
  __shared__ unsigned short tile[64][72];
  __shared__ float sPol[64];
  const int bh = blockIdx.y;
  const int b = bh / 12, h = bh % 12;
  const int n0 = blockIdx.x * 64;
  const int t = threadIdx.x;
  if (t < 64) sPol[t] = policy[b * 1024 + n0 + t];
  {
    const int nr = t >> 2, dc = (t & 3) * 16;
    const unsigned short* src = qkv + (long)(b * 1024 + n0 + nr) * 2304 + 2 * 768 + h * 64 + dc;
    float4 v0 = *(const float4*)src;
    float4 v1 = *(const float4*)(src + 8);
    *(float4*)&tile[nr][dc] = v0;
    *(float4*)&tile[nr][dc + 8] = v1;
  }
  __syncthreads();
  {
    const int d = t >> 2, nc = (t & 3) * 16;
    __align__(16) unsigned short o[16];
#pragma unroll
    for (int jj = 0; jj < 16; jj++) {
      const int cc = nc + jj;
      const int cl = (cc & 32) + sigma_inv(cc & 31);
      o[jj] = f2bf(bf2f(tile[cl][d]) * sPol[cl]);
    }
    unsigned short* dst = vTp + (long)(bh * 64 + d) * 1024 + n0 + nc;
    *(float4*)dst = *(float4*)&o[0];
    *(float4*)(dst + 8) = *(float4*)&o[8];
  }
}

// ---------- attention v20: paired-chunk steps — 16 barriers instead of 32 ----------
// History: v8 42us | v12 100us FAIL (reg-direct uncoalesced; LDS staging IS the coalescer) |
//   v13/v14 NULL (counted-vmcnt axis dead — DMA latency never exposed) |
//   v16 41.0 WIN (reg-K prefetch) | v17 51.5 FAIL (64q/wave starves TLP at 6 waves/CU) |
//   v18 <41.1 WIN (ping-pong unroll + v_cvt_pk_bf16_f32) — BANKED BEST, total 177.3 |
//   v19 CORRECTNESS FAIL (V-reg-prefetch across barrier; axis closed).
// v20: two 32-ctx chunks per barrier interval. Buffer pairs {0,1}/{2,3} alternate
//   consume/stage roles per step — disjoint by construction:
//     RAW: staged DMAs drained by step-end vmcnt(0) before the barrier;
//     WAR: barrier separates all reads of a pair from next step's DMA writes to it.
//   K-reg prefetch kept: chunk 2s preloaded after prev barrier, chunk 2s+1 mid-step
//   (its LDS valid since the previous barrier). Numerics bit-identical to v18.
__global__ __launch_bounds__(256, 3) void attn_kernel(const unsigned short* __restrict__ qkv,
                                                      const unsigned short* __restrict__ vTp,
                                                      const unsigned short* __restrict__ pbf,
                                                      const float* __restrict__ policy,
                                                      unsigned short* __restrict__ aout) {
  __shared__ __align__(16) unsigned short sK[4][2048];  // 32 ctx x 64 d, slot cb = c ^ (row&7)
  __shared__ __align__(16) unsigned short sV[4][2048];  // 64 d x 32 ctx, slot cb = c ^ ((d^(d>>2))&3)
  __shared__ __align__(16) unsigned short sPv[1024];
  __shared__ float sD[4][32];
  const int bid = blockIdx.x;
  const int bh = bid % 96, qt = bid / 96;  // bh-fast for XCD L2 locality
  const int b = bh / 12, h = bh % 12;
  const int tid = threadIdx.x;
  const int wave = tid >> 6, lane = tid & 63;
  const int qd = lane >> 4, l15 = lane & 15;
  const int q0 = qt * 128 + wave * 32;
  const unsigned short* qb = qkv + (long)(b * 1024 + q0 + l15) * 2304 + h * 64 + qd * 8;
  bf16x8 qf00 = *(const bf16x8*)qb;  // Q pre-scaled by 0.125*log2e
  bf16x8 qf01 = *(const bf16x8*)(qb + 32);
  bf16x8 qf10 = *(const bf16x8*)(qb + (long)16 * 2304);
  bf16x8 qf11 = *(const bf16x8*)(qb + (long)16 * 2304 + 32);
  if (tid < 128) *(float4*)(sPv + tid * 8) = *(const float4*)(pbf + b * 1024 + tid * 8);
  const int krow = wave * 8 + (lane >> 3);
  const int kcb = (lane & 7) ^ (lane >> 3);
  const unsigned short* kgl = qkv + (long)(b * 1024 + krow) * 2304 + 768 + h * 64 + kcb * 8;
  const int vrow = tid >> 2;
  const int vcb = (tid & 3) ^ ((vrow ^ (vrow >> 2)) & 3);
  const unsigned short* vgl = vTp + (long)(bh * 64 + vrow) * 1024 + vcb * 8;
  const int x7 = l15 & 7;
  const int vsw = (qd ^ ((l15 ^ (l15 >> 2)) & 3)) * 8;
  const int ko0 = ((0 + qd) ^ x7) * 8, ko1 = ((4 + qd) ^ x7) * 8;  // K frag column slots
  floatx4 O0[4] = {}, O1[4] = {};
  floatx4 Dl0 = {}, Dl1 = {};
  const floatx4 z = {0.f, 0.f, 0.f, 0.f};
  // prologue: stage chunks 0,1 into bufs 0,1; full drain + publish
  gll16(kgl, &sK[0][wave * 512]);
  gll16(vgl, &sV[0][wave * 512]);
  gll16(kgl + (long)32 * 2304, &sK[1][wave * 512]);
  gll16(vgl + 32, &sV[1][wave * 512]);
  asm volatile("s_waitcnt vmcnt(0) lgkmcnt(0)" ::: "memory");
  __builtin_amdgcn_s_barrier();
  asm volatile("" ::: "memory");
  // preload chunk 0's K fragments
  bf16x8 kA00 = *(const bf16x8*)&sK[0][(0 + l15) * 64 + ko0];
  bf16x8 kA01 = *(const bf16x8*)&sK[0][(0 + l15) * 64 + ko1];
  bf16x8 kA10 = *(const bf16x8*)&sK[0][(16 + l15) * 64 + ko0];
  bf16x8 kA11 = *(const bf16x8*)&sK[0][(16 + l15) * 64 + ko1];
  // one 32-ctx chunk of compute: QK(regs) -> exp/pack -> V(LDS buf) -> PV
  auto chunk = [&](int c0, int vb, bf16x8 k00, bf16x8 k01, bf16x8 k10, bf16x8 k11) {
    bf16x8 pv = *(const bf16x8*)&sPv[c0 + qd * 8];
    __builtin_amdgcn_s_setprio(1);
    floatx4 tA0 = mfma16(k01, qf01, mfma16(k00, qf00, z));
    floatx4 tB0 = mfma16(k11, qf01, mfma16(k10, qf00, z));
    floatx4 tA1 = mfma16(k01, qf11, mfma16(k00, qf10, z));
    floatx4 tB1 = mfma16(k11, qf11, mfma16(k10, qf10, z));
    __builtin_amdgcn_s_setprio(0);
    uint4 pu0, pu1;
    pu0.x = cvtpk(fexp2(tA0[0]), fexp2(tA0[1]));
    pu0.y = cvtpk(fexp2(tA0[2]), fexp2(tA0[3]));
    pu0.z = cvtpk(fexp2(tB0[0]), fexp2(tB0[1]));
    pu0.w = cvtpk(fexp2(tB0[2]), fexp2(tB0[3]));
    pu1.x = cvtpk(fexp2(tA1[0]), fexp2(tA1[1]));
    pu1.y = cvtpk(fexp2(tA1[2]), fexp2(tA1[3]));
    pu1.z = cvtpk(fexp2(tB1[0]), fexp2(tB1[1]));
    pu1.w = cvtpk(fexp2(tB1[2]), fexp2(tB1[3]));
    bf16x8 pf0 = *(bf16x8*)&pu0;
    bf16x8 pf1 = *(bf16x8*)&pu1;
    bf16x8 vf0 = *(const bf16x8*)&sV[vb][(0 * 16 + l15) * 32 + vsw];
    bf16x8 vf1 = *(const bf16x8*)&sV[vb][(1 * 16 + l15) * 32 + vsw];
    bf16x8 vf2 = *(const bf16x8*)&sV[vb][(2 * 16 + l15) * 32 + vsw];
    bf16x8 vf3 = *(const bf16x8*)&sV[vb][(3 * 16 + l15) * 32 + vsw];
    __builtin_amdgcn_s_setprio(1);
    Dl0 = mfma16(pf0, pv, Dl0);
    Dl1 = mfma16(pf1, pv, Dl1);
    O0[0] = mfma16(pf0, vf0, O0[0]); O1[0] = mfma16(pf1, vf0, O1[0]);
    O0[1] = mfma16(pf0, vf1, O0[1]); O1[1] = mfma16(pf1, vf1, O1[1]);
    O0[2] = mfma16(pf0, vf2, O0[2]); O1[2] = mfma16(pf1, vf2, O1[2]);
    O0[3] = mfma16(pf0, vf3, O0[3]); O1[3] = mfma16(pf1, vf3, O1[3]);
    __builtin_amdgcn_s_setprio(0);
  };
#pragma unroll 1
  for (int s = 0; s < 16; ++s) {
    const int cb0 = (s & 1) ? 2 : 0;  // buf of chunk 2s
    const int cb1 = cb0 + 1;          // buf of chunk 2s+1
    if (s < 15) {  // stage chunks 2s+2, 2s+3 into the OTHER buffer pair (cb0^2, cb1^2)
      const long co = (long)(64 * s + 64);
      gll16(kgl + co * 2304, &sK[cb0 ^ 2][wave * 512]);
      gll16(vgl + co, &sV[cb0 ^ 2][wave * 512]);
      gll16(kgl + (co + 32) * 2304, &sK[cb1 ^ 2][wave * 512]);
      gll16(vgl + co + 32, &sV[cb1 ^ 2][wave * 512]);
    }
    // chunk 2s from preloaded regs; mid-step preload chunk 2s+1's K frags (LDS valid
    // since previous barrier) — retires under chunk 2s's exp/pack/PV
    bf16x8 kB00 = *(const bf16x8*)&sK[cb1][(0 + l15) * 64 + ko0];
    bf16x8 kB01 = *(const bf16x8*)&sK[cb1][(0 + l15) * 64 + ko1];
    bf16x8 kB10 = *(const bf16x8*)&sK[cb1][(16 + l15) * 64 + ko0];
    bf16x8 kB11 = *(const bf16x8*)&sK[cb1][(16 + l15) * 64 + ko1];
    chunk(64 * s, cb0, kA00, kA01, kA10, kA11);
    chunk(64 * s + 32, cb1, kB00, kB01, kB10, kB11);
    // single drain + barrier per 2 chunks: staged DMAs (issued at step start) retired
    asm volatile("s_waitcnt vmcnt(0)" ::: "memory");
    __builtin_amdgcn_s_barrier();
    asm volatile("" ::: "memory");
    if (s < 15) {  // preload next step's first chunk (2s+2, buf cb0^2 — just published)
      kA00 = *(const bf16x8*)&sK[cb0 ^ 2][(0 + l15) * 64 + ko0];
      kA01 = *(const bf16x8*)&sK[cb0 ^ 2][(0 + l15) * 64 + ko1];
      kA10 = *(const bf16x8*)&sK[cb0 ^ 2][(16 + l15) * 64 + ko0];
      kA11 = *(const bf16x8*)&sK[cb0 ^ 2][(16 + l15) * 64 + ko1];
    }
  }
  // ---- diagonal correction: O[q] += e_qq(1-p_q) V[q]; l_q += e_qq(1-p_q) ----
  {
    const unsigned short* kd = qkv + (long)(b * 1024 + q0 + l15) * 2304 + 768 + h * 64 + qd * 8;
    bf16x8 kd00 = *(const bf16x8*)kd;
    bf16x8 kd01 = *(const bf16x8*)(kd + 32);
    bf16x8 kd10 = *(const bf16x8*)(kd + (long)16 * 2304);
    bf16x8 kd11 = *(const bf16x8*)(kd + (long)16 * 2304 + 32);
    float part0 = 0.f, part1 = 0.f;
#pragma unroll
    for (int jj = 0; jj < 8; jj++) {
      part0 += (float)qf00[jj] * (float)kd00[jj] + (float)qf01[jj] * (float)kd01[jj];
      part1 += (float)qf10[jj] * (float)kd10[jj] + (float)qf11[jj] * (float)kd11[jj];
    }
    part0 += __shfl_xor(part0, 16); part0 += __shfl_xor(part0, 32);
    part1 += __shfl_xor(part1, 16); part1 += __shfl_xor(part1, 32);
    const float p0 = policy[b * 1024 + q0 + l15];
    const float p1 = policy[b * 1024 + q0 + 16 + l15];
    if (qd == 0) {
      sD[wave][l15] = fexp2(part0) * (1.0f - p0);
      sD[wave][16 + l15] = fexp2(part1) * (1.0f - p1);
    }
    __builtin_amdgcn_s_waitcnt(0);
    const unsigned short* vdiag = qkv + (long)(b * 1024 + q0) * 2304 + 1536 + h * 64 + l15;
#pragma unroll
    for (int r = 0; r < 4; r++) {
      const int row = qd * 4 + r;
      const float c0v = sD[wave][row], c1v = sD[wave][16 + row];
#pragma unroll
      for (int j = 0; j < 4; j++) {
        O0[j][r] += c0v * bf2f(vdiag[(long)row * 2304 + j * 16]);
        O1[j][r] += c1v * bf2f(vdiag[(long)(16 + row) * 2304 + j * 16]);
      }
      Dl0[r] += c0v;
      Dl1[r] += c1v;
    }
  }
  const long ob = (long)(b * 1024 + q0 + qd * 4) * 768 + h * 64 + l15;
#pragma unroll
  for (int r = 0; r < 4; r++) {
    const float li0 = 1.0f / (Dl0[r] + EPSF);
    const float li1 = 1.0f / (Dl1[r] + EPSF);
#pragma unroll
    for (int j = 0; j < 4; j++) {
      aout[ob + (long)r * 768 + j * 16] = f2bf(O0[j][r] * li0);
      aout[ob + (long)(16 * 768) + r * 768 + j * 16] = f2bf(O1[j][r] * li1);
    }
  }
}

extern "C" void kernel_launch(void* const* d_in, const int* in_sizes, int n_in,
                              void* d_out, int out_size, void* d_ws, size_t ws_size,
                              hipStream_t stream) {
  const float* x      = (const float*)d_in[0];   // [8,1024,768]
  const float* policy = (const float*)d_in[1];   // [8,1024,1]
  const float* qkv_w  = (const float*)d_in[2];   // [2304,768]
  const float* proj_w = (const float*)d_in[3];   // [768,768]
  const float* proj_b = (const float*)d_in[4];   // [768]
  float* out = (float*)d_out;                    // [8,1024,768] fp32

  char* ws = (char*)d_ws;
  unsigned short* xb    = (unsigned short*)(ws + 0);         // 12,582,912 B
  unsigned short* wqkv  = (unsigned short*)(ws + 12582912);  //  3,538,944 B
  unsigned short* wproj = (unsigned short*)(ws + 16121856);  //  1,179,648 B
  unsigned short* qkvb  = (unsigned short*)(ws + 17301504);  // 37,748,736 B
  unsigned short* vTp   = (unsigned short*)(ws + 55050240);  // 12,582,912 B
  unsigned short* aoutb = (unsigned short*)(ws + 67633152);  // 12,582,912 B
  unsigned short* pbf   = (unsigned short*)(ws + 80216064);  //     16,384 B

  prep_kernel<<<4256, 256, 0, stream>>>(x, qkv_w, proj_w, policy, xb, wqkv, wproj, pbf);
  gemm_bt<0, 128, 4><<<dim3(18 * 64), 256, 0, stream>>>(xb, wqkv, qkvb, nullptr, 8192, 2304, 768);
  transpose_v<<<dim3(16, 96), 256, 0, stream>>>(qkvb, policy, vTp);
  attn_kernel<<<dim3(768), 256, 0, stream>>>(qkvb, vTp, pbf, policy, aoutb);
  gemm_bt<1, 64, 3><<<dim3(12 * 64), 256, 0, stream>>>(aoutb, wproj, out, proj_b, 8192, 768, 768);
}